// Round 9
// baseline (1205.537 us; speedup 1.0000x reference)
//
#include <hip/hip_runtime.h>

// Frequency-domain room sim, fused producer-consumer.
//   SF = DFT(sound_field) per cell (unnormalized); per block b:
//     T = clip(res,0,1) * (SF + DFT(env_b));  mic_b = IDFT(T[mic])/1024;
//     SF = box3x3x3(T)   (pointwise per bin -> recursion independent per bin)
// k_fused (1024 WGs, 4/CU):
//   P1-role (512 WGs, 8 cells each): loops b=0..15; env FFT (2 real cells per
//     complex lane, 2 float4 buffers), RAW slot-order fp16 spectra -> Et[b],
//     repacked fp16 tf -> TFt[b]; publish done[b] via threadfence+atomicAdd.
//     tf row 0 = (bin0, bin512), row 256 = (bin1, 0), rows 1..255 standard.
//   P2-role (512 WGs, one per bin; WG0 = bins {0,512} packed real pair):
//     spins on done[b] (device-scope acquire), conj-split in regs, fp32
//     recursion in regs, box via z-regs + single fp32 LDS buffer (3 bars).
//   Et/TFt stay L3-resident (12.6 MB/block working set) instead of HBM.
// k_p3: 16 inverse FFTs of the mic spectra.

#define NFFT   1024
#define NF     513
#define NKP    257
#define NCELLS 4096
#define NPAIR  2048
#define MICQ   136      // x*16+y = 8*16+8
#define PI2    6.28318530717958647692f

__device__ __forceinline__ int IDX4(int i) { return i + (i >> 3) + (i >> 6); }
__device__ __forceinline__ float clip01(float v) { return fminf(fmaxf(v, 0.0f), 1.0f); }
__device__ __forceinline__ unsigned pkh2(float a, float b) {
    union { _Float16 h[2]; unsigned u; } z;
    z.h[0] = (_Float16)a; z.h[1] = (_Float16)b;
    return z.u;
}
__device__ __forceinline__ float h2lo(unsigned u) {
    union { unsigned u; _Float16 h[2]; } z; z.u = u; return (float)z.h[0];
}
__device__ __forceinline__ float h2hi(unsigned u) {
    union { unsigned u; _Float16 h[2]; } z; z.u = u; return (float)z.h[1];
}
__device__ __forceinline__ unsigned cmp4(const uint4& v, int c) {
    return c == 0 ? v.x : c == 1 ? v.y : c == 2 ? v.z : v.w;
}
__device__ __forceinline__ unsigned sel16(const uint4& a, const uint4& b,
                                          const uint4& c, const uint4& d, int i) {
    return cmp4(i < 4 ? a : i < 8 ? b : i < 12 ? c : d, i & 3);
}
__device__ __forceinline__ float f4c(const float4& v, int c) {
    return c == 0 ? v.x : c == 1 ? v.y : c == 2 ? v.z : v.w;
}
__device__ __forceinline__ float4 f4add(float4 a, float4 b) {
    return make_float4(a.x + b.x, a.y + b.y, a.z + b.z, a.w + b.w);
}
__device__ __forceinline__ float4 f4sub(float4 a, float4 b) {
    return make_float4(a.x - b.x, a.y - b.y, a.z - b.z, a.w - b.w);
}
__device__ __forceinline__ float4 cmul2(float4 d, float2 w) {
    return make_float4(d.x * w.x - d.y * w.y, d.x * w.y + d.y * w.x,
                       d.z * w.x - d.w * w.y, d.z * w.y + d.w * w.x);
}

__global__ __launch_bounds__(256, 4) void k_fused(
    const float* __restrict__ tf, const float* __restrict__ imp,
    const float* __restrict__ noise, unsigned* __restrict__ Et,
    unsigned* __restrict__ TFt, float2* __restrict__ ms,
    unsigned* __restrict__ done_)
{
    __shared__ float4 pool[2336];          // 37376 B, shared by both roles

    const int tid  = threadIdx.x;
    const int bid  = blockIdx.x;
    const int xcd  = bid & 7, slot = bid >> 3;

    if (slot < 64) {
        // ================= P1 role: producer =================
        const int c0 = (xcd * 64 + slot) << 3;   // groups of 4 WGs share an XCD+Et line
        float4* FD0 = pool;
        float4* FD1 = pool + 1168;

        float2 tu0[5], tu1[5], tl[5];
        #pragma unroll
        for (int p = 0; p < 5; ++p) {
            const int lgU = 9 - 2 * p, lgL = lgU - 1, LL = 1 << lgL;
            const int j = tid & (LL - 1);
            const int iu0 = j << (9 - lgU), iu1 = (j + LL) << (9 - lgU), il = j << (9 - lgL);
            float s, c;
            __sincosf(-PI2 * (1.0f / 1024.0f) * (float)iu0, &s, &c); tu0[p] = make_float2(c, s);
            __sincosf(-PI2 * (1.0f / 1024.0f) * (float)iu1, &s, &c); tu1[p] = make_float2(c, s);
            __sincosf(-PI2 * (1.0f / 1024.0f) * (float)il,  &s, &c); tl[p]  = make_float2(c, s);
        }

        int lo_[4], hi_[4]; float w_[4];
        #pragma unroll
        for (int c = 0; c < 4; ++c) {
            int n = 4 * tid + c;
            float coord = (n + 0.5f) * (16.0f / 1024.0f) - 0.5f;
            coord = fminf(fmaxf(coord, 0.0f), 15.0f);
            int lo = (int)coord;
            lo_[c] = lo;
            hi_[c] = lo + 1 > 15 ? 15 : lo + 1;
            w_[c]  = coord - (float)lo;
        }

        #pragma unroll 1
        for (int b = 0; b < 16; ++b) {
            // env = clip(interp(imp),0,1)*noise, 8 cells
            const float* ipr = imp + ((size_t)b * NCELLS + c0) * 16;
            float4 nz[8];
            #pragma unroll
            for (int cc = 0; cc < 8; ++cc)
                nz[cc] = *(const float4*)(noise + ((size_t)b * NCELLS + c0 + cc) * NFFT + 4 * tid);
            #pragma unroll
            for (int c = 0; c < 4; ++c) {
                int n = 4 * tid + c;
                float wl = w_[c], wh = 1.0f - wl;
                float e[8];
                #pragma unroll
                for (int cc = 0; cc < 8; ++cc)
                    e[cc] = clip01(ipr[16 * cc + lo_[c]] * wh + ipr[16 * cc + hi_[c]] * wl) * f4c(nz[cc], c);
                FD0[IDX4(n)] = make_float4(e[0], e[1], e[2], e[3]);
                FD1[IDX4(n)] = make_float4(e[4], e[5], e[6], e[7]);
            }
            __syncthreads();

            // 10 radix-2 DIF stages fused 2/pass, both buffers per barrier
            #pragma unroll
            for (int p = 0; p < 5; ++p) {
                const int lgU = 9 - 2 * p, lgL = lgU - 1, LL = 1 << lgL;
                const int j = tid & (LL - 1), g = tid >> lgL;
                const int base = (g << (lgL + 2)) + j;
                const int q0 = IDX4(base), q1 = IDX4(base + LL);
                const int q2 = IDX4(base + 2 * LL), q3 = IDX4(base + 3 * LL);
                const float2 w0 = tu0[p], w1 = tu1[p], wl = tl[p];
                {
                    float4 a0 = FD0[q0], a1 = FD0[q1], a2 = FD0[q2], a3 = FD0[q3];
                    float4 u0 = f4add(a0, a2), d0 = f4sub(a0, a2);
                    float4 u2 = cmul2(d0, w0);
                    float4 u1 = f4add(a1, a3), d1 = f4sub(a1, a3);
                    float4 u3 = cmul2(d1, w1);
                    FD0[q0] = f4add(u0, u1);
                    FD0[q1] = cmul2(f4sub(u0, u1), wl);
                    FD0[q2] = f4add(u2, u3);
                    FD0[q3] = cmul2(f4sub(u2, u3), wl);
                }
                {
                    float4 a0 = FD1[q0], a1 = FD1[q1], a2 = FD1[q2], a3 = FD1[q3];
                    float4 u0 = f4add(a0, a2), d0 = f4sub(a0, a2);
                    float4 u2 = cmul2(d0, w0);
                    float4 u1 = f4add(a1, a3), d1 = f4sub(a1, a3);
                    float4 u3 = cmul2(d1, w1);
                    FD1[q0] = f4add(u0, u1);
                    FD1[q1] = cmul2(f4sub(u0, u1), wl);
                    FD1[q2] = f4add(u2, u3);
                    FD1[q3] = cmul2(f4sub(u2, u3), wl);
                }
                __syncthreads();
            }

            // extract: linear slot read -> fp16 pack -> 16B coalesced store
            #pragma unroll
            for (int it = 0; it < 4; ++it) {
                int s = tid + it * 256;
                float4 F0 = FD0[IDX4(s)], F1 = FD1[IDX4(s)];
                uint4 u = { pkh2(F0.x, F0.y), pkh2(F0.z, F0.w),
                            pkh2(F1.x, F1.y), pkh2(F1.z, F1.w) };
                *(uint4*)(Et + ((size_t)b * NFFT + s) * NPAIR + (c0 >> 1)) = u;
            }

            // tf: row0 = (bin0, bin512), row256 = (bin1, 0), else (2kp, 2kp+1)
            {
                const float* r_[8];
                #pragma unroll
                for (int cc = 0; cc < 8; ++cc)
                    r_[cc] = tf + ((size_t)b * NCELLS + c0 + cc) * NF;
                #pragma unroll 1
                for (int kp = tid; kp < NKP; kp += 256) {
                    int iA = 2 * kp, iB = 2 * kp + 1;
                    bool hv = true;
                    if (kp == 0)        { iA = 0;  iB = 512; }
                    else if (kp == 256) { iA = 1;  hv = false; }
                    uint4 ua, ub;
                    ua.x = pkh2(clip01(r_[0][iA]), hv ? clip01(r_[0][iB]) : 0.0f);
                    ua.y = pkh2(clip01(r_[1][iA]), hv ? clip01(r_[1][iB]) : 0.0f);
                    ua.z = pkh2(clip01(r_[2][iA]), hv ? clip01(r_[2][iB]) : 0.0f);
                    ua.w = pkh2(clip01(r_[3][iA]), hv ? clip01(r_[3][iB]) : 0.0f);
                    ub.x = pkh2(clip01(r_[4][iA]), hv ? clip01(r_[4][iB]) : 0.0f);
                    ub.y = pkh2(clip01(r_[5][iA]), hv ? clip01(r_[5][iB]) : 0.0f);
                    ub.z = pkh2(clip01(r_[6][iA]), hv ? clip01(r_[6][iB]) : 0.0f);
                    ub.w = pkh2(clip01(r_[7][iA]), hv ? clip01(r_[7][iB]) : 0.0f);
                    unsigned* dst = TFt + ((size_t)b * NKP + kp) * NCELLS + c0;
                    *(uint4*)dst = ua;
                    *(uint4*)(dst + 4) = ub;
                }
            }

            __syncthreads();   // all stores drained (vmcnt0 before barrier)
            if (tid == 0) { __threadfence(); atomicAdd(&done_[b], 1u); }
        }
    } else {
        // ================= P2 role: consumer =================
        const int k2   = xcd * 64 + (slot - 64);     // 0..511
        const bool dual = (k2 == 0);                 // bins {0, 512} packed real
        const int rA = dual ? 0 : (__brev(k2) >> 22);
        const int rB = dual ? 1 : (__brev((1024 - k2) & 1023) >> 22);
        const int kp = dual ? 0 : (k2 == 1 ? 256 : (k2 >> 1));
        const int sel = (k2 <= 1) ? 0 : (k2 & 1);
        const int q = tid, x = q >> 4, y = q & 15;
        float2* Sz = (float2*)pool;                  // 4352 float2 = 34816 B

        float2 SF[16];
        #pragma unroll
        for (int z = 0; z < 16; ++z) SF[z] = make_float2(0.f, 0.f);

        #pragma unroll 1
        for (int b = 0; b < 16; ++b) {
            if (tid == 0) {
                while (__hip_atomic_load(&done_[b], __ATOMIC_RELAXED,
                                         __HIP_MEMORY_SCOPE_AGENT) < 512u)
                    __builtin_amdgcn_s_sleep(16);
                __threadfence();                     // acquire: inv stale L1/L2
            }
            __syncthreads();

            const uint4* ea = (const uint4*)(Et + ((size_t)b * NFFT + rA) * NPAIR + (q << 3));
            const uint4* eb = (const uint4*)(Et + ((size_t)b * NFFT + rB) * NPAIR + (q << 3));
            const uint4* tp = (const uint4*)(TFt + ((size_t)b * NKP + kp) * NCELLS + (q << 4));
            uint4 FA0 = ea[0], FA1 = ea[1];
            uint4 FB0 = eb[0], FB1 = eb[1];
            uint4 TA0 = tp[0], TA1 = tp[1], TA2 = tp[2], TA3 = tp[3];

            float2 T[16];
            if (!dual) {
                #pragma unroll
                for (int j = 0; j < 8; ++j) {
                    unsigned fu = cmp4(j < 4 ? FA0 : FA1, j & 3);
                    unsigned gu = cmp4(j < 4 ? FB0 : FB1, j & 3);
                    float fr = h2lo(fu), fi = h2hi(fu);
                    float gr = h2lo(gu), gi = h2hi(gu);
                    float ear = 0.5f * (fr + gr), eai = 0.5f * (fi - gi);
                    float ebr = 0.5f * (fi + gi), ebi = 0.5f * (gr - fr);
                    unsigned te = sel16(TA0, TA1, TA2, TA3, 2 * j);
                    unsigned to = sel16(TA0, TA1, TA2, TA3, 2 * j + 1);
                    float re_ = sel ? h2hi(te) : h2lo(te);
                    float ro_ = sel ? h2hi(to) : h2lo(to);
                    T[2 * j]     = make_float2(re_ * (SF[2 * j].x + ear),
                                               re_ * (SF[2 * j].y + eai));
                    T[2 * j + 1] = make_float2(ro_ * (SF[2 * j + 1].x + ebr),
                                               ro_ * (SF[2 * j + 1].y + ebi));
                }
            } else {
                // bins 0 (.x) and 512 (.y), both exactly real
                #pragma unroll
                for (int j = 0; j < 8; ++j) {
                    unsigned fu = cmp4(j < 4 ? FA0 : FA1, j & 3);   // F(0)
                    unsigned gu = cmp4(j < 4 ? FB0 : FB1, j & 3);   // F(512)
                    unsigned te = sel16(TA0, TA1, TA2, TA3, 2 * j);     // (tf0, tf512)
                    unsigned to = sel16(TA0, TA1, TA2, TA3, 2 * j + 1);
                    T[2 * j]     = make_float2(h2lo(te) * (SF[2 * j].x + h2lo(fu)),
                                               h2hi(te) * (SF[2 * j].y + h2lo(gu)));
                    T[2 * j + 1] = make_float2(h2lo(to) * (SF[2 * j + 1].x + h2hi(fu)),
                                               h2hi(to) * (SF[2 * j + 1].y + h2hi(gu)));
                }
            }
            if (q == MICQ) {
                if (dual) {
                    ms[b * NF + 0]   = make_float2(T[8].x, 0.0f);
                    ms[b * NF + 512] = make_float2(T[8].y, 0.0f);
                } else {
                    ms[b * NF + k2] = T[8];
                }
            }

            // z-sum in place (rolling prev)
            {
                float2 p = make_float2(0.f, 0.f);
                #pragma unroll
                for (int z = 0; z < 16; ++z) {
                    float2 c = T[z];
                    float2 s = make_float2(c.x + p.x, c.y + p.y);
                    if (z < 15) { s.x += T[z + 1].x; s.y += T[z + 1].y; }
                    T[z] = s;
                    p = c;
                }
            }

            // y-sum, then x-sum, through the single fp32 buffer (3 barriers)
            #pragma unroll
            for (int z = 0; z < 16; ++z) Sz[q * 17 + z] = T[z];
            __syncthreads();
            #pragma unroll
            for (int z = 0; z < 16; ++z) {
                float2 s = T[z];
                if (y > 0)  { float2 u = Sz[(q - 1) * 17 + z]; s.x += u.x; s.y += u.y; }
                if (y < 15) { float2 u = Sz[(q + 1) * 17 + z]; s.x += u.x; s.y += u.y; }
                T[z] = s;
            }
            __syncthreads();                 // reads done before overwrite
            #pragma unroll
            for (int z = 0; z < 16; ++z) Sz[q * 17 + z] = T[z];
            __syncthreads();
            #pragma unroll
            for (int z = 0; z < 16; ++z) {
                float2 s = T[z];
                if (x > 0)  { float2 u = Sz[(q - 16) * 17 + z]; s.x += u.x; s.y += u.y; }
                if (x < 15) { float2 u = Sz[(q + 16) * 17 + z]; s.x += u.x; s.y += u.y; }
                SF[z] = s;
            }
            // next iter's first Sz write is fenced by its spin-syncthreads
        }
    }
}

// ---------------- P3 ----------------
__device__ __forceinline__ int pd(int i) { return i + (i >> 5); }

__global__ __launch_bounds__(256) void k_p3(
    const float2* __restrict__ ms, float* __restrict__ out)
{
    __shared__ float2 FD[1056];
    const int b = blockIdx.x, tid = threadIdx.x;

    for (int j = tid; j < NFFT; j += 256) {
        int jj = (j <= 512) ? j : 1024 - j;
        float2 v = ms[b * NF + jj];
        if (j > 512) v.y = -v.y;
        FD[pd(__brev(j) >> 22)] = v;
    }
    __syncthreads();

    for (int lg = 0; lg <= 9; ++lg) {
        const int len = 1 << lg;
        for (int pr = tid; pr < 512; pr += 256) {
            const int jj = pr & (len - 1);
            const int i0 = ((pr >> lg) << (lg + 1)) + jj;
            const int i1 = i0 + len;
            const int iw = jj << (9 - lg);
            float sn, cs;
            __sincosf(-PI2 * (1.0f / 1024.0f) * (float)iw, &sn, &cs);
            float2 a = FD[pd(i0)], bb = FD[pd(i1)];
            float tr = bb.x * cs + bb.y * sn;
            float ti = bb.y * cs - bb.x * sn;
            FD[pd(i0)] = make_float2(a.x + tr, a.y + ti);
            FD[pd(i1)] = make_float2(a.x - tr, a.y - ti);
        }
        __syncthreads();
    }
    for (int t = tid; t < NFFT; t += 256)
        out[b * NFFT + t] = FD[pd(t)].x * (1.0f / 1024.0f);
}

extern "C" void kernel_launch(void* const* d_in, const int* in_sizes, int n_in,
                              void* d_out, int out_size, void* d_ws, size_t ws_size,
                              hipStream_t stream)
{
    const float* tf    = (const float*)d_in[1];
    const float* imp   = (const float*)d_in[2];
    const float* noise = (const float*)d_in[3];
    float* out = (float*)d_out;

    unsigned* Et    = (unsigned*)d_ws;                            // 16*1024*2048 u32
    unsigned* TFt   = Et + (size_t)16 * NFFT * NPAIR;             // 16*257*4096 u32
    float2*   ms    = (float2*)(TFt + (size_t)16 * NKP * NCELLS); // 16*513 c64
    unsigned* done_ = (unsigned*)(ms + 16 * NF);                  // 16 u32 flags

    hipMemsetAsync(done_, 0, 16 * sizeof(unsigned), stream);
    k_fused<<<1024, 256, 0, stream>>>(tf, imp, noise, Et, TFt, ms, done_);
    k_p3<<<16, 256, 0, stream>>>(ms, out);
}

// Round 10
// 359.923 us; speedup vs baseline: 3.3494x; 3.3494x over previous
//
#include <hip/hip_runtime.h>

// Frequency-domain room sim, 3-kernel phase split.
//   SF = DFT(sound_field) per cell (unnormalized); per block b:
//     T = clip(res,0,1) * (SF + DFT(env_b));  mic_b = IDFT(T[mic])/1024;
//     SF = box3x3x3(T)   (pointwise per bin -> recursion independent per bin)
// P1: env FFTs as mixed-radix 8*8*8*2, 8 points/thread, 8 cells/WG (2 packed
//     complex buffers, 2 real cells per complex lane). Pass1 = env+radix8 in
//     REGISTERS (no input LDS write); passes 2,3 = one LDS round-trip each;
//     final radix-2 fused into the fp16 extract. 3 barriers total.
//     Output in digit-reversed slot order (8,8,8,2). XCD-chunked swizzle.
// P2: one WG per bin k (513). Rows slotof(k), slotof(1024-k); conj-split in
//     regs; fp32 recursion in regs; box via z-regs + single 34.8KB fp32 LDS
//     buffer (4 barriers/iter) -> 4 WG/CU, single generation.
// P3: 16 inverse FFTs of the mic spectra.

#define NFFT   1024
#define NF     513
#define NKP    257
#define NCELLS 4096
#define NPAIR  2048
#define MICQ   136      // x*16+y = 8*16+8
#define PI2    6.28318530717958647692f
#define RT2    0.70710678118654752f

__device__ __forceinline__ int SK(int i) { return i + (i >> 4) + (i >> 7); }
__device__ __forceinline__ int slotof(int k) {
    return ((k & 7) << 7) | (((k >> 3) & 7) << 4) | (((k >> 6) & 7) << 1) | ((k >> 9) & 1);
}
__device__ __forceinline__ float clip01(float v) { return fminf(fmaxf(v, 0.0f), 1.0f); }
__device__ __forceinline__ unsigned pkh2(float a, float b) {
    union { _Float16 h[2]; unsigned u; } z;
    z.h[0] = (_Float16)a; z.h[1] = (_Float16)b;
    return z.u;
}
__device__ __forceinline__ float h2lo(unsigned u) {
    union { unsigned u; _Float16 h[2]; } z; z.u = u; return (float)z.h[0];
}
__device__ __forceinline__ float h2hi(unsigned u) {
    union { unsigned u; _Float16 h[2]; } z; z.u = u; return (float)z.h[1];
}
__device__ __forceinline__ unsigned cmp4(const uint4& v, int c) {
    return c == 0 ? v.x : c == 1 ? v.y : c == 2 ? v.z : v.w;
}
__device__ __forceinline__ unsigned sel16(const uint4& a, const uint4& b,
                                          const uint4& c, const uint4& d, int i) {
    return cmp4(i < 4 ? a : i < 8 ? b : i < 12 ? c : d, i & 3);
}
__device__ __forceinline__ float4 f4add(float4 a, float4 b) {
    return make_float4(a.x + b.x, a.y + b.y, a.z + b.z, a.w + b.w);
}
__device__ __forceinline__ float4 f4sub(float4 a, float4 b) {
    return make_float4(a.x - b.x, a.y - b.y, a.z - b.z, a.w - b.w);
}
__device__ __forceinline__ float4 cmul2(float4 d, float2 w) {
    return make_float4(d.x * w.x - d.y * w.y, d.x * w.y + d.y * w.x,
                       d.z * w.x - d.w * w.y, d.z * w.y + d.w * w.x);
}
__device__ __forceinline__ float4 nI(float4 v) { return make_float4(v.y, -v.x, v.w, -v.z); }
__device__ __forceinline__ float4 pI(float4 v) { return make_float4(-v.y, v.x, -v.w, v.z); }
__device__ __forceinline__ float4 w81(float4 v) {   // * (1-i)/sqrt2
    return make_float4(RT2 * (v.x + v.y), RT2 * (v.y - v.x),
                       RT2 * (v.z + v.w), RT2 * (v.w - v.z));
}
__device__ __forceinline__ float4 w83(float4 v) {   // * (-1-i)/sqrt2
    return make_float4(RT2 * (v.y - v.x), RT2 * (-v.x - v.y),
                       RT2 * (v.w - v.z), RT2 * (-v.z - v.w));
}

// in-register 8-point DFT on 2 packed complexes: a[p] <- sum_m a[m] W8^{pm}
__device__ __forceinline__ void dft8(float4* a) {
    float4 c0 = f4add(a[0], a[4]), c1 = f4add(a[1], a[5]);
    float4 c2 = f4add(a[2], a[6]), c3 = f4add(a[3], a[7]);
    float4 d0 = f4sub(a[0], a[4]);
    float4 d1 = w81(f4sub(a[1], a[5]));
    float4 d2 = nI (f4sub(a[2], a[6]));
    float4 d3 = w83(f4sub(a[3], a[7]));
    float4 t0 = f4add(c0, c2), t1 = f4add(c1, c3);
    float4 t2 = f4sub(c0, c2), t3 = f4sub(c1, c3);
    float4 s0 = f4add(d0, d2), s1 = f4add(d1, d3);
    float4 s2 = f4sub(d0, d2), s3 = f4sub(d1, d3);
    a[0] = f4add(t0, t1);      a[4] = f4sub(t0, t1);
    a[2] = f4add(t2, nI(t3));  a[6] = f4add(t2, pI(t3));
    a[1] = f4add(s0, s1);      a[5] = f4sub(s0, s1);
    a[3] = f4add(s2, nI(s3));  a[7] = f4add(s2, pI(s3));
}

// apply W_L^{j*p} to a[1..7] via chained complex mul (w1 = W_L^j)
__device__ __forceinline__ void twiddle7(float4* a, int j, float invL) {
    float sv, cv;
    __sincosf(-PI2 * (float)j * invL, &sv, &cv);
    float2 w1 = make_float2(cv, sv), wp = w1;
    a[1] = cmul2(a[1], wp);
    #pragma unroll
    for (int p = 2; p < 8; ++p) {
        wp = make_float2(wp.x * w1.x - wp.y * w1.y, wp.x * w1.y + wp.y * w1.x);
        a[p] = cmul2(a[p], wp);
    }
}

// ---------------- P1 ----------------
// WG = (block b, 8 cells). 256 threads: threads 0-127 buffer 0 (cells c0..c0+3),
// threads 128-255 buffer 1 (cells c0+4..c0+7). Grid 8192.
__global__ __launch_bounds__(256) void k_p1(
    const float* __restrict__ tf, const float* __restrict__ imp,
    const float* __restrict__ noise, unsigned* __restrict__ Et,
    unsigned* __restrict__ TFt)
{
    __shared__ float4 FD[2][1100];     // SK(1023)=1093

    const int tid = threadIdx.x;
    const int bid = blockIdx.x;
    const int w   = ((bid & 7) << 10) | (bid >> 3);   // XCD-chunked swizzle
    const int b   = w >> 9;
    const int c0  = (w & 511) << 3;
    const int buf = tid >> 7, j1 = tid & 127;
    const int cb  = c0 + 4 * buf;

    // ---- env + pass1 (L=1024, stride 128) entirely from registers ----
    {
        const float* ipr = imp   + ((size_t)b * NCELLS + cb) * 16;
        const float* nz  = noise + ((size_t)b * NCELLS + cb) * (size_t)NFFT;
        float4 a[8];
        #pragma unroll
        for (int m = 0; m < 8; ++m) {
            int n = j1 + (m << 7);
            float coord = (n + 0.5f) * (16.0f / 1024.0f) - 0.5f;
            coord = fminf(fmaxf(coord, 0.0f), 15.0f);
            int lo = (int)coord;
            int hi = lo + 1 > 15 ? 15 : lo + 1;
            float wl = coord - (float)lo, wh = 1.0f - wl;
            float4 e;
            e.x = clip01(ipr[lo]      * wh + ipr[hi]      * wl) * nz[n];
            e.y = clip01(ipr[16 + lo] * wh + ipr[16 + hi] * wl) * nz[NFFT + n];
            e.z = clip01(ipr[32 + lo] * wh + ipr[32 + hi] * wl) * nz[2 * NFFT + n];
            e.w = clip01(ipr[48 + lo] * wh + ipr[48 + hi] * wl) * nz[3 * NFFT + n];
            a[m] = e;
        }
        dft8(a);
        twiddle7(a, j1, 1.0f / 1024.0f);
        #pragma unroll
        for (int p = 0; p < 8; ++p) FD[buf][SK(j1 + (p << 7))] = a[p];
    }
    __syncthreads();

    // ---- pass2: L=128, stride 16 ----
    {
        const int idx0 = ((j1 >> 4) << 7) + (j1 & 15);
        float4 a[8];
        #pragma unroll
        for (int m = 0; m < 8; ++m) a[m] = FD[buf][SK(idx0 + (m << 4))];
        dft8(a);
        twiddle7(a, j1 & 15, 1.0f / 128.0f);
        #pragma unroll
        for (int p = 0; p < 8; ++p) FD[buf][SK(idx0 + (p << 4))] = a[p];
    }
    __syncthreads();

    // ---- pass3: L=16, stride 2 ----
    {
        const int idx0 = ((j1 >> 1) << 4) + (j1 & 1);
        float4 a[8];
        #pragma unroll
        for (int m = 0; m < 8; ++m) a[m] = FD[buf][SK(idx0 + (m << 1))];
        dft8(a);
        twiddle7(a, j1 & 1, 1.0f / 16.0f);
        #pragma unroll
        for (int p = 0; p < 8; ++p) FD[buf][SK(idx0 + (p << 1))] = a[p];
    }
    __syncthreads();

    // ---- pass4 (radix-2, stride 1, trivial twiddle) fused into extract ----
    #pragma unroll
    for (int it = 0; it < 2; ++it) {
        int p = tid + (it << 8);                 // pair 0..511
        float4 A0 = FD[0][SK(2 * p)], B0 = FD[0][SK(2 * p + 1)];
        float4 A1 = FD[1][SK(2 * p)], B1 = FD[1][SK(2 * p + 1)];
        float4 y00 = f4add(A0, B0), y10 = f4sub(A0, B0);
        float4 y01 = f4add(A1, B1), y11 = f4sub(A1, B1);
        uint4 u0 = { pkh2(y00.x, y00.y), pkh2(y00.z, y00.w),
                     pkh2(y01.x, y01.y), pkh2(y01.z, y01.w) };
        uint4 u1 = { pkh2(y10.x, y10.y), pkh2(y10.z, y10.w),
                     pkh2(y11.x, y11.y), pkh2(y11.z, y11.w) };
        unsigned* base = Et + ((size_t)b * NFFT + 2 * p) * NPAIR + (c0 >> 1);
        *(uint4*)base = u0;
        *(uint4*)(base + NPAIR) = u1;
    }

    // ---- tf: clip + pack bin pairs for 8 cells ----
    {
        const float* r_[8];
        #pragma unroll
        for (int cc = 0; cc < 8; ++cc)
            r_[cc] = tf + ((size_t)b * NCELLS + c0 + cc) * NF;
        for (int kp = tid; kp < NKP; kp += 256) {
            bool hv = kp < 256;
            uint4 ua, ub;
            ua.x = pkh2(clip01(r_[0][2 * kp]), hv ? clip01(r_[0][2 * kp + 1]) : 0.0f);
            ua.y = pkh2(clip01(r_[1][2 * kp]), hv ? clip01(r_[1][2 * kp + 1]) : 0.0f);
            ua.z = pkh2(clip01(r_[2][2 * kp]), hv ? clip01(r_[2][2 * kp + 1]) : 0.0f);
            ua.w = pkh2(clip01(r_[3][2 * kp]), hv ? clip01(r_[3][2 * kp + 1]) : 0.0f);
            ub.x = pkh2(clip01(r_[4][2 * kp]), hv ? clip01(r_[4][2 * kp + 1]) : 0.0f);
            ub.y = pkh2(clip01(r_[5][2 * kp]), hv ? clip01(r_[5][2 * kp + 1]) : 0.0f);
            ub.z = pkh2(clip01(r_[6][2 * kp]), hv ? clip01(r_[6][2 * kp + 1]) : 0.0f);
            ub.w = pkh2(clip01(r_[7][2 * kp]), hv ? clip01(r_[7][2 * kp + 1]) : 0.0f);
            unsigned* dst = TFt + ((size_t)b * NKP + kp) * NCELLS + c0;
            *(uint4*)dst = ua;
            *(uint4*)(dst + 4) = ub;
        }
    }
}

// ---------------- P2 ----------------
// Grid 513, one WG per bin k. Thread q owns z-column of (x,y)=(q>>4,q&15)
// = pairs q*8..q*8+7. Reads slot rows slotof(k), slotof(1024-k); conj-split
// in regs; box via z-regs + single fp32 LDS buffer, 4 barriers/iter.
__global__ __launch_bounds__(256) void k_p2(
    const unsigned* __restrict__ Et, const unsigned* __restrict__ TFt,
    float2* __restrict__ ms)
{
    __shared__ float2 Sz[256 * 17];    // 34816 B -> 4 WG/CU

    const int q  = threadIdx.x;
    const int k  = blockIdx.x;
    const int kp = k >> 1, sel = k & 1;
    const int x  = q >> 4, y = q & 15;
    const int rA = slotof(k);
    const int rB = slotof((1024 - k) & 1023);

    float2 SF[16];
    #pragma unroll
    for (int z = 0; z < 16; ++z) SF[z] = make_float2(0.f, 0.f);

    uint4 FA[2][2], FB[2][2], TB[2][4];
    {
        const uint4* ea = (const uint4*)(Et + (size_t)rA * NPAIR + (q << 3));
        const uint4* eb = (const uint4*)(Et + (size_t)rB * NPAIR + (q << 3));
        const uint4* tp = (const uint4*)(TFt + (size_t)kp * NCELLS + (q << 4));
        FA[0][0] = ea[0]; FA[0][1] = ea[1];
        FB[0][0] = eb[0]; FB[0][1] = eb[1];
        TB[0][0] = tp[0]; TB[0][1] = tp[1]; TB[0][2] = tp[2]; TB[0][3] = tp[3];
    }

    #pragma unroll
    for (int b = 0; b < 16; ++b) {
        const int cur = b & 1, nxt = cur ^ 1;
        if (b + 1 < 16) {
            const uint4* ea = (const uint4*)(Et + ((size_t)(b + 1) * NFFT + rA) * NPAIR + (q << 3));
            const uint4* eb = (const uint4*)(Et + ((size_t)(b + 1) * NFFT + rB) * NPAIR + (q << 3));
            const uint4* tp = (const uint4*)(TFt + ((size_t)(b + 1) * NKP + kp) * NCELLS + (q << 4));
            FA[nxt][0] = ea[0]; FA[nxt][1] = ea[1];
            FB[nxt][0] = eb[0]; FB[nxt][1] = eb[1];
            TB[nxt][0] = tp[0]; TB[nxt][1] = tp[1]; TB[nxt][2] = tp[2]; TB[nxt][3] = tp[3];
        }

        // conj-split + T = r * (SF + E), per pair j (cells z=2j, 2j+1)
        float2 T[16];
        #pragma unroll
        for (int j = 0; j < 8; ++j) {
            unsigned fu = cmp4(j < 4 ? FA[cur][0] : FA[cur][1], j & 3);
            unsigned gu = cmp4(j < 4 ? FB[cur][0] : FB[cur][1], j & 3);
            float fr = h2lo(fu), fi = h2hi(fu);
            float gr = h2lo(gu), gi = h2hi(gu);
            float ear = 0.5f * (fr + gr), eai = 0.5f * (fi - gi);
            float ebr = 0.5f * (fi + gi), ebi = 0.5f * (gr - fr);
            unsigned te = sel16(TB[cur][0], TB[cur][1], TB[cur][2], TB[cur][3], 2 * j);
            unsigned to = sel16(TB[cur][0], TB[cur][1], TB[cur][2], TB[cur][3], 2 * j + 1);
            float re_ = sel ? h2hi(te) : h2lo(te);
            float ro_ = sel ? h2hi(to) : h2lo(to);
            T[2 * j]     = make_float2(re_ * (SF[2 * j].x + ear),
                                       re_ * (SF[2 * j].y + eai));
            T[2 * j + 1] = make_float2(ro_ * (SF[2 * j + 1].x + ebr),
                                       ro_ * (SF[2 * j + 1].y + ebi));
        }
        if (q == MICQ) ms[b * NF + k] = T[8];

        // z-sum in place (rolling prev)
        {
            float2 p = make_float2(0.f, 0.f);
            #pragma unroll
            for (int z = 0; z < 16; ++z) {
                float2 c = T[z];
                float2 s = make_float2(c.x + p.x, c.y + p.y);
                if (z < 15) { s.x += T[z + 1].x; s.y += T[z + 1].y; }
                T[z] = s;
                p = c;
            }
        }

        // y-sum then x-sum via single fp32 buffer, 4 barriers
        #pragma unroll
        for (int z = 0; z < 16; ++z) Sz[q * 17 + z] = T[z];
        __syncthreads();
        #pragma unroll
        for (int z = 0; z < 16; ++z) {
            float2 s = T[z];
            if (y > 0)  { float2 u = Sz[(q - 1) * 17 + z]; s.x += u.x; s.y += u.y; }
            if (y < 15) { float2 u = Sz[(q + 1) * 17 + z]; s.x += u.x; s.y += u.y; }
            T[z] = s;
        }
        __syncthreads();                 // y-reads done before overwrite
        #pragma unroll
        for (int z = 0; z < 16; ++z) Sz[q * 17 + z] = T[z];
        __syncthreads();
        #pragma unroll
        for (int z = 0; z < 16; ++z) {
            float2 s = T[z];
            if (x > 0)  { float2 u = Sz[(q - 16) * 17 + z]; s.x += u.x; s.y += u.y; }
            if (x < 15) { float2 u = Sz[(q + 16) * 17 + z]; s.x += u.x; s.y += u.y; }
            SF[z] = s;
        }
        __syncthreads();                 // x-reads done before next iter write
    }
}

// ---------------- P3 ----------------
__device__ __forceinline__ int pd(int i) { return i + (i >> 5); }

__global__ __launch_bounds__(256) void k_p3(
    const float2* __restrict__ ms, float* __restrict__ out)
{
    __shared__ float2 FD[1056];
    const int b = blockIdx.x, tid = threadIdx.x;

    for (int j = tid; j < NFFT; j += 256) {
        int jj = (j <= 512) ? j : 1024 - j;
        float2 v = ms[b * NF + jj];
        if (j > 512) v.y = -v.y;
        FD[pd(__brev(j) >> 22)] = v;
    }
    __syncthreads();

    for (int lg = 0; lg <= 9; ++lg) {
        const int len = 1 << lg;
        for (int pr = tid; pr < 512; pr += 256) {
            const int jj = pr & (len - 1);
            const int i0 = ((pr >> lg) << (lg + 1)) + jj;
            const int i1 = i0 + len;
            const int iw = jj << (9 - lg);
            float sn, cs;
            __sincosf(-PI2 * (1.0f / 1024.0f) * (float)iw, &sn, &cs);
            float2 a = FD[pd(i0)], bb = FD[pd(i1)];
            float tr = bb.x * cs + bb.y * sn;
            float ti = bb.y * cs - bb.x * sn;
            FD[pd(i0)] = make_float2(a.x + tr, a.y + ti);
            FD[pd(i1)] = make_float2(a.x - tr, a.y - ti);
        }
        __syncthreads();
    }
    for (int t = tid; t < NFFT; t += 256)
        out[b * NFFT + t] = FD[pd(t)].x * (1.0f / 1024.0f);
}

extern "C" void kernel_launch(void* const* d_in, const int* in_sizes, int n_in,
                              void* d_out, int out_size, void* d_ws, size_t ws_size,
                              hipStream_t stream)
{
    const float* tf    = (const float*)d_in[1];
    const float* imp   = (const float*)d_in[2];
    const float* noise = (const float*)d_in[3];
    float* out = (float*)d_out;

    unsigned* Et  = (unsigned*)d_ws;                              // 16*1024*2048 u32
    unsigned* TFt = Et + (size_t)16 * NFFT * NPAIR;               // 16*257*4096 u32
    float2*   ms  = (float2*)(TFt + (size_t)16 * NKP * NCELLS);   // 16*513 c64

    k_p1<<<8192, 256, 0, stream>>>(tf, imp, noise, Et, TFt);
    k_p2<<<NF, 256, 0, stream>>>(Et, TFt, ms);
    k_p3<<<16, 256, 0, stream>>>(ms, out);
}

// Round 11
// 348.546 us; speedup vs baseline: 3.4588x; 1.0326x over previous
//
#include <hip/hip_runtime.h>

// Frequency-domain room sim, 3-kernel phase split.
//   SF = DFT(sound_field) per cell (unnormalized); per block b:
//     T = clip(res,0,1) * (SF + DFT(env_b));  mic_b = IDFT(T[mic])/1024;
//     SF = box3x3x3(T)   (pointwise per bin -> recursion independent per bin)
// P1: env FFTs as mixed-radix 8*8*8*2, 8 points/thread, 8 cells/WG (2 packed
//     complex buffers, 2 real cells per complex lane). Pass1 = env+radix8 in
//     REGISTERS; passes 2,3 = one LDS round-trip each; final radix-2 fused
//     into the fp16 extract. 3 barriers. Digit-reversed (8,8,8,2) slot order.
//     launch_bounds(256,4): LDS caps us at 4 WG/CU anyway -> 128 VGPRs free;
//     noise loads batched into regs (32 independent dwords) before interp.
// P2: one WG per bin k (513). Rows slotof(k), slotof(1024-k); conj-split in
//     regs; fp32 recursion in regs; box via z-regs + single 34.8KB fp32 LDS
//     buffer (4 barriers/iter) -> 4 WG/CU, single generation.
// P3: 16 inverse FFTs of the mic spectra.

#define NFFT   1024
#define NF     513
#define NKP    257
#define NCELLS 4096
#define NPAIR  2048
#define MICQ   136      // x*16+y = 8*16+8
#define PI2    6.28318530717958647692f
#define RT2    0.70710678118654752f

__device__ __forceinline__ int SK(int i) { return i + (i >> 4) + (i >> 7); }
__device__ __forceinline__ int slotof(int k) {
    return ((k & 7) << 7) | (((k >> 3) & 7) << 4) | (((k >> 6) & 7) << 1) | ((k >> 9) & 1);
}
__device__ __forceinline__ float clip01(float v) { return fminf(fmaxf(v, 0.0f), 1.0f); }
__device__ __forceinline__ unsigned pkh2(float a, float b) {
    union { _Float16 h[2]; unsigned u; } z;
    z.h[0] = (_Float16)a; z.h[1] = (_Float16)b;
    return z.u;
}
__device__ __forceinline__ float h2lo(unsigned u) {
    union { unsigned u; _Float16 h[2]; } z; z.u = u; return (float)z.h[0];
}
__device__ __forceinline__ float h2hi(unsigned u) {
    union { unsigned u; _Float16 h[2]; } z; z.u = u; return (float)z.h[1];
}
__device__ __forceinline__ unsigned cmp4(const uint4& v, int c) {
    return c == 0 ? v.x : c == 1 ? v.y : c == 2 ? v.z : v.w;
}
__device__ __forceinline__ unsigned sel16(const uint4& a, const uint4& b,
                                          const uint4& c, const uint4& d, int i) {
    return cmp4(i < 4 ? a : i < 8 ? b : i < 12 ? c : d, i & 3);
}
__device__ __forceinline__ float4 f4add(float4 a, float4 b) {
    return make_float4(a.x + b.x, a.y + b.y, a.z + b.z, a.w + b.w);
}
__device__ __forceinline__ float4 f4sub(float4 a, float4 b) {
    return make_float4(a.x - b.x, a.y - b.y, a.z - b.z, a.w - b.w);
}
__device__ __forceinline__ float4 cmul2(float4 d, float2 w) {
    return make_float4(d.x * w.x - d.y * w.y, d.x * w.y + d.y * w.x,
                       d.z * w.x - d.w * w.y, d.z * w.y + d.w * w.x);
}
__device__ __forceinline__ float4 nI(float4 v) { return make_float4(v.y, -v.x, v.w, -v.z); }
__device__ __forceinline__ float4 pI(float4 v) { return make_float4(-v.y, v.x, -v.w, v.z); }
__device__ __forceinline__ float4 w81(float4 v) {   // * (1-i)/sqrt2
    return make_float4(RT2 * (v.x + v.y), RT2 * (v.y - v.x),
                       RT2 * (v.z + v.w), RT2 * (v.w - v.z));
}
__device__ __forceinline__ float4 w83(float4 v) {   // * (-1-i)/sqrt2
    return make_float4(RT2 * (v.y - v.x), RT2 * (-v.x - v.y),
                       RT2 * (v.w - v.z), RT2 * (-v.z - v.w));
}

// in-register 8-point DFT on 2 packed complexes: a[p] <- sum_m a[m] W8^{pm}
__device__ __forceinline__ void dft8(float4* a) {
    float4 c0 = f4add(a[0], a[4]), c1 = f4add(a[1], a[5]);
    float4 c2 = f4add(a[2], a[6]), c3 = f4add(a[3], a[7]);
    float4 d0 = f4sub(a[0], a[4]);
    float4 d1 = w81(f4sub(a[1], a[5]));
    float4 d2 = nI (f4sub(a[2], a[6]));
    float4 d3 = w83(f4sub(a[3], a[7]));
    float4 t0 = f4add(c0, c2), t1 = f4add(c1, c3);
    float4 t2 = f4sub(c0, c2), t3 = f4sub(c1, c3);
    float4 s0 = f4add(d0, d2), s1 = f4add(d1, d3);
    float4 s2 = f4sub(d0, d2), s3 = f4sub(d1, d3);
    a[0] = f4add(t0, t1);      a[4] = f4sub(t0, t1);
    a[2] = f4add(t2, nI(t3));  a[6] = f4add(t2, pI(t3));
    a[1] = f4add(s0, s1);      a[5] = f4sub(s0, s1);
    a[3] = f4add(s2, nI(s3));  a[7] = f4add(s2, pI(s3));
}

// apply W_L^{j*p} to a[1..7] via chained complex mul (w1 = W_L^j)
__device__ __forceinline__ void twiddle7(float4* a, int j, float invL) {
    float sv, cv;
    __sincosf(-PI2 * (float)j * invL, &sv, &cv);
    float2 w1 = make_float2(cv, sv), wp = w1;
    a[1] = cmul2(a[1], wp);
    #pragma unroll
    for (int p = 2; p < 8; ++p) {
        wp = make_float2(wp.x * w1.x - wp.y * w1.y, wp.x * w1.y + wp.y * w1.x);
        a[p] = cmul2(a[p], wp);
    }
}

// ---------------- P1 ----------------
// WG = (block b, 8 cells). 256 threads: threads 0-127 buffer 0 (cells c0..c0+3),
// threads 128-255 buffer 1 (cells c0+4..c0+7). Grid 8192.
__global__ __launch_bounds__(256, 4) void k_p1(
    const float* __restrict__ tf, const float* __restrict__ imp,
    const float* __restrict__ noise, unsigned* __restrict__ Et,
    unsigned* __restrict__ TFt)
{
    __shared__ float4 FD[2][1100];     // SK(1023)=1093

    const int tid = threadIdx.x;
    const int bid = blockIdx.x;
    const int w   = ((bid & 7) << 10) | (bid >> 3);   // XCD-chunked swizzle
    const int b   = w >> 9;
    const int c0  = (w & 511) << 3;
    const int buf = tid >> 7, j1 = tid & 127;
    const int cb  = c0 + 4 * buf;

    // ---- env + pass1 (L=1024, stride 128) entirely from registers ----
    {
        // batch all 32 noise loads first: independent, coalesced, deep in flight
        const float* nz = noise + ((size_t)b * NCELLS + cb) * (size_t)NFFT;
        float nzv[32];
        #pragma unroll
        for (int m = 0; m < 8; ++m) {
            #pragma unroll
            for (int cc = 0; cc < 4; ++cc)
                nzv[4 * m + cc] = nz[cc * NFFT + j1 + (m << 7)];
        }

        // interp env (ipr loads are L1-hot broadcasts; VALU overlaps noise)
        const float* ipr = imp + ((size_t)b * NCELLS + cb) * 16;
        float4 a[8];
        #pragma unroll
        for (int m = 0; m < 8; ++m) {
            int n = j1 + (m << 7);
            float coord = (n + 0.5f) * (16.0f / 1024.0f) - 0.5f;
            coord = fminf(fmaxf(coord, 0.0f), 15.0f);
            int lo = (int)coord;
            int hi = lo + 1 > 15 ? 15 : lo + 1;
            float wl = coord - (float)lo, wh = 1.0f - wl;
            float4 e;
            e.x = clip01(ipr[lo]      * wh + ipr[hi]      * wl) * nzv[4 * m + 0];
            e.y = clip01(ipr[16 + lo] * wh + ipr[16 + hi] * wl) * nzv[4 * m + 1];
            e.z = clip01(ipr[32 + lo] * wh + ipr[32 + hi] * wl) * nzv[4 * m + 2];
            e.w = clip01(ipr[48 + lo] * wh + ipr[48 + hi] * wl) * nzv[4 * m + 3];
            a[m] = e;
        }
        dft8(a);
        twiddle7(a, j1, 1.0f / 1024.0f);
        #pragma unroll
        for (int p = 0; p < 8; ++p) FD[buf][SK(j1 + (p << 7))] = a[p];
    }
    __syncthreads();

    // ---- pass2: L=128, stride 16 ----
    {
        const int idx0 = ((j1 >> 4) << 7) + (j1 & 15);
        float4 a[8];
        #pragma unroll
        for (int m = 0; m < 8; ++m) a[m] = FD[buf][SK(idx0 + (m << 4))];
        dft8(a);
        twiddle7(a, j1 & 15, 1.0f / 128.0f);
        #pragma unroll
        for (int p = 0; p < 8; ++p) FD[buf][SK(idx0 + (p << 4))] = a[p];
    }
    __syncthreads();

    // ---- pass3: L=16, stride 2 ----
    {
        const int idx0 = ((j1 >> 1) << 4) + (j1 & 1);
        float4 a[8];
        #pragma unroll
        for (int m = 0; m < 8; ++m) a[m] = FD[buf][SK(idx0 + (m << 1))];
        dft8(a);
        twiddle7(a, j1 & 1, 1.0f / 16.0f);
        #pragma unroll
        for (int p = 0; p < 8; ++p) FD[buf][SK(idx0 + (p << 1))] = a[p];
    }
    __syncthreads();

    // ---- pass4 (radix-2, stride 1, trivial twiddle) fused into extract ----
    #pragma unroll
    for (int it = 0; it < 2; ++it) {
        int p = tid + (it << 8);                 // pair 0..511
        float4 A0 = FD[0][SK(2 * p)], B0 = FD[0][SK(2 * p + 1)];
        float4 A1 = FD[1][SK(2 * p)], B1 = FD[1][SK(2 * p + 1)];
        float4 y00 = f4add(A0, B0), y10 = f4sub(A0, B0);
        float4 y01 = f4add(A1, B1), y11 = f4sub(A1, B1);
        uint4 u0 = { pkh2(y00.x, y00.y), pkh2(y00.z, y00.w),
                     pkh2(y01.x, y01.y), pkh2(y01.z, y01.w) };
        uint4 u1 = { pkh2(y10.x, y10.y), pkh2(y10.z, y10.w),
                     pkh2(y11.x, y11.y), pkh2(y11.z, y11.w) };
        unsigned* base = Et + ((size_t)b * NFFT + 2 * p) * NPAIR + (c0 >> 1);
        *(uint4*)base = u0;
        *(uint4*)(base + NPAIR) = u1;
    }

    // ---- tf: clip + pack bin pairs for 8 cells ----
    {
        const float* r_[8];
        #pragma unroll
        for (int cc = 0; cc < 8; ++cc)
            r_[cc] = tf + ((size_t)b * NCELLS + c0 + cc) * NF;
        for (int kp = tid; kp < NKP; kp += 256) {
            bool hv = kp < 256;
            uint4 ua, ub;
            ua.x = pkh2(clip01(r_[0][2 * kp]), hv ? clip01(r_[0][2 * kp + 1]) : 0.0f);
            ua.y = pkh2(clip01(r_[1][2 * kp]), hv ? clip01(r_[1][2 * kp + 1]) : 0.0f);
            ua.z = pkh2(clip01(r_[2][2 * kp]), hv ? clip01(r_[2][2 * kp + 1]) : 0.0f);
            ua.w = pkh2(clip01(r_[3][2 * kp]), hv ? clip01(r_[3][2 * kp + 1]) : 0.0f);
            ub.x = pkh2(clip01(r_[4][2 * kp]), hv ? clip01(r_[4][2 * kp + 1]) : 0.0f);
            ub.y = pkh2(clip01(r_[5][2 * kp]), hv ? clip01(r_[5][2 * kp + 1]) : 0.0f);
            ub.z = pkh2(clip01(r_[6][2 * kp]), hv ? clip01(r_[6][2 * kp + 1]) : 0.0f);
            ub.w = pkh2(clip01(r_[7][2 * kp]), hv ? clip01(r_[7][2 * kp + 1]) : 0.0f);
            unsigned* dst = TFt + ((size_t)b * NKP + kp) * NCELLS + c0;
            *(uint4*)dst = ua;
            *(uint4*)(dst + 4) = ub;
        }
    }
}

// ---------------- P2 ----------------
// Grid 513, one WG per bin k. Thread q owns z-column of (x,y)=(q>>4,q&15)
// = pairs q*8..q*8+7. Reads slot rows slotof(k), slotof(1024-k); conj-split
// in regs; box via z-regs + single fp32 LDS buffer, 4 barriers/iter.
__global__ __launch_bounds__(256, 4) void k_p2(
    const unsigned* __restrict__ Et, const unsigned* __restrict__ TFt,
    float2* __restrict__ ms)
{
    __shared__ float2 Sz[256 * 17];    // 34816 B -> 4 WG/CU

    const int q  = threadIdx.x;
    const int k  = blockIdx.x;
    const int kp = k >> 1, sel = k & 1;
    const int x  = q >> 4, y = q & 15;
    const int rA = slotof(k);
    const int rB = slotof((1024 - k) & 1023);

    float2 SF[16];
    #pragma unroll
    for (int z = 0; z < 16; ++z) SF[z] = make_float2(0.f, 0.f);

    uint4 FA[2][2], FB[2][2], TB[2][4];
    {
        const uint4* ea = (const uint4*)(Et + (size_t)rA * NPAIR + (q << 3));
        const uint4* eb = (const uint4*)(Et + (size_t)rB * NPAIR + (q << 3));
        const uint4* tp = (const uint4*)(TFt + (size_t)kp * NCELLS + (q << 4));
        FA[0][0] = ea[0]; FA[0][1] = ea[1];
        FB[0][0] = eb[0]; FB[0][1] = eb[1];
        TB[0][0] = tp[0]; TB[0][1] = tp[1]; TB[0][2] = tp[2]; TB[0][3] = tp[3];
    }

    #pragma unroll
    for (int b = 0; b < 16; ++b) {
        const int cur = b & 1, nxt = cur ^ 1;
        if (b + 1 < 16) {
            const uint4* ea = (const uint4*)(Et + ((size_t)(b + 1) * NFFT + rA) * NPAIR + (q << 3));
            const uint4* eb = (const uint4*)(Et + ((size_t)(b + 1) * NFFT + rB) * NPAIR + (q << 3));
            const uint4* tp = (const uint4*)(TFt + ((size_t)(b + 1) * NKP + kp) * NCELLS + (q << 4));
            FA[nxt][0] = ea[0]; FA[nxt][1] = ea[1];
            FB[nxt][0] = eb[0]; FB[nxt][1] = eb[1];
            TB[nxt][0] = tp[0]; TB[nxt][1] = tp[1]; TB[nxt][2] = tp[2]; TB[nxt][3] = tp[3];
        }

        // conj-split + T = r * (SF + E), per pair j (cells z=2j, 2j+1)
        float2 T[16];
        #pragma unroll
        for (int j = 0; j < 8; ++j) {
            unsigned fu = cmp4(j < 4 ? FA[cur][0] : FA[cur][1], j & 3);
            unsigned gu = cmp4(j < 4 ? FB[cur][0] : FB[cur][1], j & 3);
            float fr = h2lo(fu), fi = h2hi(fu);
            float gr = h2lo(gu), gi = h2hi(gu);
            float ear = 0.5f * (fr + gr), eai = 0.5f * (fi - gi);
            float ebr = 0.5f * (fi + gi), ebi = 0.5f * (gr - fr);
            unsigned te = sel16(TB[cur][0], TB[cur][1], TB[cur][2], TB[cur][3], 2 * j);
            unsigned to = sel16(TB[cur][0], TB[cur][1], TB[cur][2], TB[cur][3], 2 * j + 1);
            float re_ = sel ? h2hi(te) : h2lo(te);
            float ro_ = sel ? h2hi(to) : h2lo(to);
            T[2 * j]     = make_float2(re_ * (SF[2 * j].x + ear),
                                       re_ * (SF[2 * j].y + eai));
            T[2 * j + 1] = make_float2(ro_ * (SF[2 * j + 1].x + ebr),
                                       ro_ * (SF[2 * j + 1].y + ebi));
        }
        if (q == MICQ) ms[b * NF + k] = T[8];

        // z-sum in place (rolling prev)
        {
            float2 p = make_float2(0.f, 0.f);
            #pragma unroll
            for (int z = 0; z < 16; ++z) {
                float2 c = T[z];
                float2 s = make_float2(c.x + p.x, c.y + p.y);
                if (z < 15) { s.x += T[z + 1].x; s.y += T[z + 1].y; }
                T[z] = s;
                p = c;
            }
        }

        // y-sum then x-sum via single fp32 buffer, 4 barriers
        #pragma unroll
        for (int z = 0; z < 16; ++z) Sz[q * 17 + z] = T[z];
        __syncthreads();
        #pragma unroll
        for (int z = 0; z < 16; ++z) {
            float2 s = T[z];
            if (y > 0)  { float2 u = Sz[(q - 1) * 17 + z]; s.x += u.x; s.y += u.y; }
            if (y < 15) { float2 u = Sz[(q + 1) * 17 + z]; s.x += u.x; s.y += u.y; }
            T[z] = s;
        }
        __syncthreads();                 // y-reads done before overwrite
        #pragma unroll
        for (int z = 0; z < 16; ++z) Sz[q * 17 + z] = T[z];
        __syncthreads();
        #pragma unroll
        for (int z = 0; z < 16; ++z) {
            float2 s = T[z];
            if (x > 0)  { float2 u = Sz[(q - 16) * 17 + z]; s.x += u.x; s.y += u.y; }
            if (x < 15) { float2 u = Sz[(q + 16) * 17 + z]; s.x += u.x; s.y += u.y; }
            SF[z] = s;
        }
        __syncthreads();                 // x-reads done before next iter write
    }
}

// ---------------- P3 ----------------
__device__ __forceinline__ int pd(int i) { return i + (i >> 5); }

__global__ __launch_bounds__(256) void k_p3(
    const float2* __restrict__ ms, float* __restrict__ out)
{
    __shared__ float2 FD[1056];
    const int b = blockIdx.x, tid = threadIdx.x;

    for (int j = tid; j < NFFT; j += 256) {
        int jj = (j <= 512) ? j : 1024 - j;
        float2 v = ms[b * NF + jj];
        if (j > 512) v.y = -v.y;
        FD[pd(__brev(j) >> 22)] = v;
    }
    __syncthreads();

    for (int lg = 0; lg <= 9; ++lg) {
        const int len = 1 << lg;
        for (int pr = tid; pr < 512; pr += 256) {
            const int jj = pr & (len - 1);
            const int i0 = ((pr >> lg) << (lg + 1)) + jj;
            const int i1 = i0 + len;
            const int iw = jj << (9 - lg);
            float sn, cs;
            __sincosf(-PI2 * (1.0f / 1024.0f) * (float)iw, &sn, &cs);
            float2 a = FD[pd(i0)], bb = FD[pd(i1)];
            float tr = bb.x * cs + bb.y * sn;
            float ti = bb.y * cs - bb.x * sn;
            FD[pd(i0)] = make_float2(a.x + tr, a.y + ti);
            FD[pd(i1)] = make_float2(a.x - tr, a.y - ti);
        }
        __syncthreads();
    }
    for (int t = tid; t < NFFT; t += 256)
        out[b * NFFT + t] = FD[pd(t)].x * (1.0f / 1024.0f);
}

extern "C" void kernel_launch(void* const* d_in, const int* in_sizes, int n_in,
                              void* d_out, int out_size, void* d_ws, size_t ws_size,
                              hipStream_t stream)
{
    const float* tf    = (const float*)d_in[1];
    const float* imp   = (const float*)d_in[2];
    const float* noise = (const float*)d_in[3];
    float* out = (float*)d_out;

    unsigned* Et  = (unsigned*)d_ws;                              // 16*1024*2048 u32
    unsigned* TFt = Et + (size_t)16 * NFFT * NPAIR;               // 16*257*4096 u32
    float2*   ms  = (float2*)(TFt + (size_t)16 * NKP * NCELLS);   // 16*513 c64

    k_p1<<<8192, 256, 0, stream>>>(tf, imp, noise, Et, TFt);
    k_p2<<<NF, 256, 0, stream>>>(Et, TFt, ms);
    k_p3<<<16, 256, 0, stream>>>(ms, out);
}

// Round 12
// 264.418 us; speedup vs baseline: 4.5592x; 1.3182x over previous
//
#include <hip/hip_runtime.h>

// Frequency-domain room sim, 3-kernel phase split.
//   SF = DFT(sound_field) per cell (unnormalized); per block b:
//     T = clip(res,0,1) * (SF + DFT(env_b));  mic_b = IDFT(T[mic])/1024;
//     SF = box3x3x3(T)   (pointwise per bin -> recursion independent per bin)
// P1: mixed-radix 8*8*8*2 env FFTs, 8 cells/WG, XOR-swizzled 32KB LDS
//     (exactly 2x1024 float4) -> 5 WG/CU. 3 barriers. Digit-reversed slots.
// P2: 512 WGs x 1024 threads (2 WG/CU = 32 waves/CU). Thread owns a 4-z slab;
//     z-exchange via in-wave shfl (partner q+-1), y/x via 32KB XOR-swizzled
//     LDS buffer, 4 barriers/iter. WG0 = bins {0,512} packed real pair.
// P3: 16 inverse FFTs of the mic spectra.

#define NFFT   1024
#define NF     513
#define NKP    257
#define NCELLS 4096
#define NPAIR  2048
#define PI2    6.28318530717958647692f
#define RT2    0.70710678118654752f

// float4-index XOR swizzle: i mod 8 uniform across lanes for strides
// {1,2,16,128} (pass3's stride-2 gets mixed by bits 4-6 of the base).
__device__ __forceinline__ int SW(int i) {
    return i ^ ((i >> 4) & 7) ^ ((i >> 7) & 7);
}
__device__ __forceinline__ int slotof(int k) {
    return ((k & 7) << 7) | (((k >> 3) & 7) << 4) | (((k >> 6) & 7) << 1) | ((k >> 9) & 1);
}
__device__ __forceinline__ float clip01(float v) { return fminf(fmaxf(v, 0.0f), 1.0f); }
__device__ __forceinline__ unsigned pkh2(float a, float b) {
    union { _Float16 h[2]; unsigned u; } z;
    z.h[0] = (_Float16)a; z.h[1] = (_Float16)b;
    return z.u;
}
__device__ __forceinline__ float h2lo(unsigned u) {
    union { unsigned u; _Float16 h[2]; } z; z.u = u; return (float)z.h[0];
}
__device__ __forceinline__ float h2hi(unsigned u) {
    union { unsigned u; _Float16 h[2]; } z; z.u = u; return (float)z.h[1];
}
__device__ __forceinline__ unsigned cmp4(const uint4& v, int c) {
    return c == 0 ? v.x : c == 1 ? v.y : c == 2 ? v.z : v.w;
}
__device__ __forceinline__ float4 f4add(float4 a, float4 b) {
    return make_float4(a.x + b.x, a.y + b.y, a.z + b.z, a.w + b.w);
}
__device__ __forceinline__ float4 f4sub(float4 a, float4 b) {
    return make_float4(a.x - b.x, a.y - b.y, a.z - b.z, a.w - b.w);
}
__device__ __forceinline__ float4 cmul2(float4 d, float2 w) {
    return make_float4(d.x * w.x - d.y * w.y, d.x * w.y + d.y * w.x,
                       d.z * w.x - d.w * w.y, d.z * w.y + d.w * w.x);
}
__device__ __forceinline__ float4 nI(float4 v) { return make_float4(v.y, -v.x, v.w, -v.z); }
__device__ __forceinline__ float4 pI(float4 v) { return make_float4(-v.y, v.x, -v.w, v.z); }
__device__ __forceinline__ float4 w81(float4 v) {
    return make_float4(RT2 * (v.x + v.y), RT2 * (v.y - v.x),
                       RT2 * (v.z + v.w), RT2 * (v.w - v.z));
}
__device__ __forceinline__ float4 w83(float4 v) {
    return make_float4(RT2 * (v.y - v.x), RT2 * (-v.x - v.y),
                       RT2 * (v.w - v.z), RT2 * (-v.z - v.w));
}

__device__ __forceinline__ void dft8(float4* a) {
    float4 c0 = f4add(a[0], a[4]), c1 = f4add(a[1], a[5]);
    float4 c2 = f4add(a[2], a[6]), c3 = f4add(a[3], a[7]);
    float4 d0 = f4sub(a[0], a[4]);
    float4 d1 = w81(f4sub(a[1], a[5]));
    float4 d2 = nI (f4sub(a[2], a[6]));
    float4 d3 = w83(f4sub(a[3], a[7]));
    float4 t0 = f4add(c0, c2), t1 = f4add(c1, c3);
    float4 t2 = f4sub(c0, c2), t3 = f4sub(c1, c3);
    float4 s0 = f4add(d0, d2), s1 = f4add(d1, d3);
    float4 s2 = f4sub(d0, d2), s3 = f4sub(d1, d3);
    a[0] = f4add(t0, t1);      a[4] = f4sub(t0, t1);
    a[2] = f4add(t2, nI(t3));  a[6] = f4add(t2, pI(t3));
    a[1] = f4add(s0, s1);      a[5] = f4sub(s0, s1);
    a[3] = f4add(s2, nI(s3));  a[7] = f4add(s2, pI(s3));
}

__device__ __forceinline__ void twiddle7(float4* a, int j, float invL) {
    float sv, cv;
    __sincosf(-PI2 * (float)j * invL, &sv, &cv);
    float2 w1 = make_float2(cv, sv), wp = w1;
    a[1] = cmul2(a[1], wp);
    #pragma unroll
    for (int p = 2; p < 8; ++p) {
        wp = make_float2(wp.x * w1.x - wp.y * w1.y, wp.x * w1.y + wp.y * w1.x);
        a[p] = cmul2(a[p], wp);
    }
}

// ---------------- P1 ----------------
__global__ __launch_bounds__(256, 5) void k_p1(
    const float* __restrict__ tf, const float* __restrict__ imp,
    const float* __restrict__ noise, unsigned* __restrict__ Et,
    unsigned* __restrict__ TFt)
{
    __shared__ float4 FD[2][1024];     // exactly 32 KB -> 5 WG/CU

    const int tid = threadIdx.x;
    const int bid = blockIdx.x;
    const int w   = ((bid & 7) << 10) | (bid >> 3);   // XCD-chunked swizzle
    const int b   = w >> 9;
    const int c0  = (w & 511) << 3;
    const int buf = tid >> 7, j1 = tid & 127;
    const int cb  = c0 + 4 * buf;

    // ---- env + pass1 (L=1024, stride 128) from registers ----
    {
        const float* nz = noise + ((size_t)b * NCELLS + cb) * (size_t)NFFT;
        float nzv[32];
        #pragma unroll
        for (int m = 0; m < 8; ++m) {
            #pragma unroll
            for (int cc = 0; cc < 4; ++cc)
                nzv[4 * m + cc] = nz[cc * NFFT + j1 + (m << 7)];
        }
        const float* ipr = imp + ((size_t)b * NCELLS + cb) * 16;
        float4 a[8];
        #pragma unroll
        for (int m = 0; m < 8; ++m) {
            int n = j1 + (m << 7);
            float coord = (n + 0.5f) * (16.0f / 1024.0f) - 0.5f;
            coord = fminf(fmaxf(coord, 0.0f), 15.0f);
            int lo = (int)coord;
            int hi = lo + 1 > 15 ? 15 : lo + 1;
            float wl = coord - (float)lo, wh = 1.0f - wl;
            float4 e;
            e.x = clip01(ipr[lo]      * wh + ipr[hi]      * wl) * nzv[4 * m + 0];
            e.y = clip01(ipr[16 + lo] * wh + ipr[16 + hi] * wl) * nzv[4 * m + 1];
            e.z = clip01(ipr[32 + lo] * wh + ipr[32 + hi] * wl) * nzv[4 * m + 2];
            e.w = clip01(ipr[48 + lo] * wh + ipr[48 + hi] * wl) * nzv[4 * m + 3];
            a[m] = e;
        }
        dft8(a);
        twiddle7(a, j1, 1.0f / 1024.0f);
        #pragma unroll
        for (int p = 0; p < 8; ++p) FD[buf][SW(j1 + (p << 7))] = a[p];
    }
    __syncthreads();

    // ---- pass2: L=128, stride 16 ----
    {
        const int idx0 = ((j1 >> 4) << 7) + (j1 & 15);
        float4 a[8];
        #pragma unroll
        for (int m = 0; m < 8; ++m) a[m] = FD[buf][SW(idx0 + (m << 4))];
        dft8(a);
        twiddle7(a, j1 & 15, 1.0f / 128.0f);
        #pragma unroll
        for (int p = 0; p < 8; ++p) FD[buf][SW(idx0 + (p << 4))] = a[p];
    }
    __syncthreads();

    // ---- pass3: L=16, stride 2 ----
    {
        const int idx0 = ((j1 >> 1) << 4) + (j1 & 1);
        float4 a[8];
        #pragma unroll
        for (int m = 0; m < 8; ++m) a[m] = FD[buf][SW(idx0 + (m << 1))];
        dft8(a);
        twiddle7(a, j1 & 1, 1.0f / 16.0f);
        #pragma unroll
        for (int p = 0; p < 8; ++p) FD[buf][SW(idx0 + (p << 1))] = a[p];
    }
    __syncthreads();

    // ---- pass4 (radix-2, stride 1) fused into fp16 extract ----
    #pragma unroll
    for (int it = 0; it < 2; ++it) {
        int p = tid + (it << 8);
        float4 A0 = FD[0][SW(2 * p)], B0 = FD[0][SW(2 * p + 1)];
        float4 A1 = FD[1][SW(2 * p)], B1 = FD[1][SW(2 * p + 1)];
        float4 y00 = f4add(A0, B0), y10 = f4sub(A0, B0);
        float4 y01 = f4add(A1, B1), y11 = f4sub(A1, B1);
        uint4 u0 = { pkh2(y00.x, y00.y), pkh2(y00.z, y00.w),
                     pkh2(y01.x, y01.y), pkh2(y01.z, y01.w) };
        uint4 u1 = { pkh2(y10.x, y10.y), pkh2(y10.z, y10.w),
                     pkh2(y11.x, y11.y), pkh2(y11.z, y11.w) };
        unsigned* base = Et + ((size_t)b * NFFT + 2 * p) * NPAIR + (c0 >> 1);
        *(uint4*)base = u0;
        *(uint4*)(base + NPAIR) = u1;
    }

    // ---- tf: clip + pack bin pairs for 8 cells ----
    {
        const float* r_[8];
        #pragma unroll
        for (int cc = 0; cc < 8; ++cc)
            r_[cc] = tf + ((size_t)b * NCELLS + c0 + cc) * NF;
        for (int kp = tid; kp < NKP; kp += 256) {
            bool hv = kp < 256;
            uint4 ua, ub;
            ua.x = pkh2(clip01(r_[0][2 * kp]), hv ? clip01(r_[0][2 * kp + 1]) : 0.0f);
            ua.y = pkh2(clip01(r_[1][2 * kp]), hv ? clip01(r_[1][2 * kp + 1]) : 0.0f);
            ua.z = pkh2(clip01(r_[2][2 * kp]), hv ? clip01(r_[2][2 * kp + 1]) : 0.0f);
            ua.w = pkh2(clip01(r_[3][2 * kp]), hv ? clip01(r_[3][2 * kp + 1]) : 0.0f);
            ub.x = pkh2(clip01(r_[4][2 * kp]), hv ? clip01(r_[4][2 * kp + 1]) : 0.0f);
            ub.y = pkh2(clip01(r_[5][2 * kp]), hv ? clip01(r_[5][2 * kp + 1]) : 0.0f);
            ub.z = pkh2(clip01(r_[6][2 * kp]), hv ? clip01(r_[6][2 * kp + 1]) : 0.0f);
            ub.w = pkh2(clip01(r_[7][2 * kp]), hv ? clip01(r_[7][2 * kp + 1]) : 0.0f);
            unsigned* dst = TFt + ((size_t)b * NKP + kp) * NCELLS + c0;
            *(uint4*)dst = ua;
            *(uint4*)(dst + 4) = ub;
        }
    }
}

// ---------------- P2 ----------------
// Grid 512 x 1024 threads (2 WG/CU = 32 waves/CU). Thread q: col = q>>2
// (x = q>>6, y = (q>>2)&15), z-slab = (q&3)*4 .. +3; pairs 2q,2q+1; cells
// 4q..4q+3 (all loads coalesced). z-exchange: partner q+-1 via in-wave shfl.
// WG0 = bins {0,512} (both exactly real): rows 0,1; tf rows kp=0 / kp=256.
__global__ __launch_bounds__(1024, 8) void k_p2(
    const unsigned* __restrict__ Et, const unsigned* __restrict__ TFt,
    float2* __restrict__ ms)
{
    __shared__ float2 Sz[4096];        // exactly 32 KB

    const int q    = threadIdx.x;
    const int lane = q & 63;
    const int k    = blockIdx.x;
    const bool dual = (k == 0);
    const int kp  = dual ? 0 : (k >> 1);
    const int sel = dual ? 0 : (k & 1);
    const int rA  = dual ? 0 : slotof(k);
    const int rB  = dual ? 1 : slotof((1024 - k) & 1023);
    const int x = q >> 6, y = (q >> 2) & 15, zs = (q & 3) << 2;

    // swizzled exchange index: bank-pair class uniform for q, q+-4, q+-64
    #define AX(qq, dz) (((qq) << 2) | ((dz) ^ ((qq) & 3) ^ (((qq) >> 2) & 3)))

    float2 SF[4];
    #pragma unroll
    for (int dz = 0; dz < 4; ++dz) SF[dz] = make_float2(0.f, 0.f);

    #pragma unroll 1
    for (int b = 0; b < 16; ++b) {
        const uint2 ea = *(const uint2*)(Et + ((size_t)b * NFFT + rA) * NPAIR + 2 * q);
        const uint2 eb = *(const uint2*)(Et + ((size_t)b * NFFT + rB) * NPAIR + 2 * q);
        const uint4 tp = *(const uint4*)(TFt + ((size_t)b * NKP + kp) * NCELLS + 4 * q);
        uint4 tp2;
        if (dual) tp2 = *(const uint4*)(TFt + ((size_t)b * NKP + 256) * NCELLS + 4 * q);

        float2 T[4];
        if (!dual) {
            #pragma unroll
            for (int j = 0; j < 2; ++j) {
                unsigned fu = j ? ea.y : ea.x;
                unsigned gu = j ? eb.y : eb.x;
                float fr = h2lo(fu), fi = h2hi(fu);
                float gr = h2lo(gu), gi = h2hi(gu);
                float ear = 0.5f * (fr + gr), eai = 0.5f * (fi - gi);
                float ebr = 0.5f * (fi + gi), ebi = 0.5f * (gr - fr);
                unsigned te = cmp4(tp, 2 * j);
                unsigned to = cmp4(tp, 2 * j + 1);
                float re_ = sel ? h2hi(te) : h2lo(te);
                float ro_ = sel ? h2hi(to) : h2lo(to);
                T[2 * j]     = make_float2(re_ * (SF[2 * j].x + ear),
                                           re_ * (SF[2 * j].y + eai));
                T[2 * j + 1] = make_float2(ro_ * (SF[2 * j + 1].x + ebr),
                                           ro_ * (SF[2 * j + 1].y + ebi));
            }
        } else {
            // bins 0 (.x) and 512 (.y); row0 = (E(0) of cell-pair), row1 = E(512)
            #pragma unroll
            for (int dz = 0; dz < 4; ++dz) {
                unsigned fu = (dz >> 1) ? ea.y : ea.x;
                unsigned gu = (dz >> 1) ? eb.y : eb.x;
                float e0   = (dz & 1) ? h2hi(fu) : h2lo(fu);
                float e512 = (dz & 1) ? h2hi(gu) : h2lo(gu);
                float tA = h2lo(cmp4(tp, dz));
                float tB = h2lo(cmp4(tp2, dz));
                T[dz] = make_float2(tA * (SF[dz].x + e0),
                                    tB * (SF[dz].y + e512));
            }
        }
        if (q == 546) {                 // cell (8,8,8): col 136, zs 8, dz 0
            if (dual) {
                ms[b * NF + 0]   = make_float2(T[0].x, 0.0f);
                ms[b * NF + 512] = make_float2(T[0].y, 0.0f);
            } else {
                ms[b * NF + k] = T[0];
            }
        }

        // z-sum: slab-internal + in-wave shfl to partners q-1 / q+1
        float2 D, U;
        D.x = __shfl(T[3].x, lane - 1, 64); D.y = __shfl(T[3].y, lane - 1, 64);
        U.x = __shfl(T[0].x, lane + 1, 64); U.y = __shfl(T[0].y, lane + 1, 64);
        float2 Z[4];
        Z[0] = make_float2(T[0].x + T[1].x + (zs > 0 ? D.x : 0.f),
                           T[0].y + T[1].y + (zs > 0 ? D.y : 0.f));
        Z[1] = make_float2(T[0].x + T[1].x + T[2].x, T[0].y + T[1].y + T[2].y);
        Z[2] = make_float2(T[1].x + T[2].x + T[3].x, T[1].y + T[2].y + T[3].y);
        Z[3] = make_float2(T[2].x + T[3].x + (zs < 12 ? U.x : 0.f),
                           T[2].y + T[3].y + (zs < 12 ? U.y : 0.f));

        // y-sum via LDS (y neighbor = q +- 4)
        #pragma unroll
        for (int dz = 0; dz < 4; ++dz) Sz[AX(q, dz)] = Z[dz];
        __syncthreads();
        #pragma unroll
        for (int dz = 0; dz < 4; ++dz) {
            float2 s = Z[dz];
            if (y > 0)  { float2 u = Sz[AX(q - 4, dz)]; s.x += u.x; s.y += u.y; }
            if (y < 15) { float2 u = Sz[AX(q + 4, dz)]; s.x += u.x; s.y += u.y; }
            Z[dz] = s;
        }
        __syncthreads();
        // x-sum via LDS (x neighbor = q +- 64)
        #pragma unroll
        for (int dz = 0; dz < 4; ++dz) Sz[AX(q, dz)] = Z[dz];
        __syncthreads();
        #pragma unroll
        for (int dz = 0; dz < 4; ++dz) {
            float2 s = Z[dz];
            if (x > 0)  { float2 u = Sz[AX(q - 64, dz)]; s.x += u.x; s.y += u.y; }
            if (x < 15) { float2 u = Sz[AX(q + 64, dz)]; s.x += u.x; s.y += u.y; }
            SF[dz] = s;
        }
        __syncthreads();                // x-reads done before next iter write
    }
    #undef AX
}

// ---------------- P3 ----------------
__device__ __forceinline__ int pd(int i) { return i + (i >> 5); }

__global__ __launch_bounds__(256) void k_p3(
    const float2* __restrict__ ms, float* __restrict__ out)
{
    __shared__ float2 FD[1056];
    const int b = blockIdx.x, tid = threadIdx.x;

    for (int j = tid; j < NFFT; j += 256) {
        int jj = (j <= 512) ? j : 1024 - j;
        float2 v = ms[b * NF + jj];
        if (j > 512) v.y = -v.y;
        FD[pd(__brev(j) >> 22)] = v;
    }
    __syncthreads();

    for (int lg = 0; lg <= 9; ++lg) {
        const int len = 1 << lg;
        for (int pr = tid; pr < 512; pr += 256) {
            const int jj = pr & (len - 1);
            const int i0 = ((pr >> lg) << (lg + 1)) + jj;
            const int i1 = i0 + len;
            const int iw = jj << (9 - lg);
            float sn, cs;
            __sincosf(-PI2 * (1.0f / 1024.0f) * (float)iw, &sn, &cs);
            float2 a = FD[pd(i0)], bb = FD[pd(i1)];
            float tr = bb.x * cs + bb.y * sn;
            float ti = bb.y * cs - bb.x * sn;
            FD[pd(i0)] = make_float2(a.x + tr, a.y + ti);
            FD[pd(i1)] = make_float2(a.x - tr, a.y - ti);
        }
        __syncthreads();
    }
    for (int t = tid; t < NFFT; t += 256)
        out[b * NFFT + t] = FD[pd(t)].x * (1.0f / 1024.0f);
}

extern "C" void kernel_launch(void* const* d_in, const int* in_sizes, int n_in,
                              void* d_out, int out_size, void* d_ws, size_t ws_size,
                              hipStream_t stream)
{
    const float* tf    = (const float*)d_in[1];
    const float* imp   = (const float*)d_in[2];
    const float* noise = (const float*)d_in[3];
    float* out = (float*)d_out;

    unsigned* Et  = (unsigned*)d_ws;                              // 16*1024*2048 u32
    unsigned* TFt = Et + (size_t)16 * NFFT * NPAIR;               // 16*257*4096 u32
    float2*   ms  = (float2*)(TFt + (size_t)16 * NKP * NCELLS);   // 16*513 c64

    k_p1<<<8192, 256, 0, stream>>>(tf, imp, noise, Et, TFt);
    k_p2<<<512, 1024, 0, stream>>>(Et, TFt, ms);
    k_p3<<<16, 256, 0, stream>>>(ms, out);
}